// Round 22
// baseline (85.574 us; speedup 1.0000x reference)
//
#include <hip/hip_runtime.h>
#include <hip/hip_bf16.h>

#define NB 8192   // B
#define ND 128    // D
#define N2 16384  // 2B

#define CPB 512               // columns per strip
#define CTILE 64              // columns staged per LDS tile
#define NT (CPB / CTILE)      // 8 tiles per block
#define TILEB (CTILE * 128)   // 8192 bytes per fp8 tile

typedef __attribute__((ext_vector_type(4))) float f32x4;
typedef __attribute__((ext_vector_type(4))) int v4i;
typedef __attribute__((ext_vector_type(8))) int v8i;

// sqrt((1/T) * log2(e)) with T=0.5 : sqrt(2.8853900817779268)
static constexpr float SQRT_C_VAL = 1.69864368f;

// ---------------- normalize + pos-dot + fp8 quantize (+ ssum zero) ----------------
__global__ __launch_bounds__(256) void nrm_kernel(const float* __restrict__ zi,
                                                  const float* __restrict__ zj,
                                                  unsigned short* __restrict__ reps8_u16,
                                                  float* __restrict__ pos,
                                                  float* __restrict__ ssum) {
    const int gtid = blockIdx.x * 256 + threadIdx.x;
    if (gtid < N2) ssum[gtid] = 0.f;  // replaces the hipMemsetAsync dispatch
    const int pair = gtid >> 6;
    const int lane = threadIdx.x & 63;
    const float2 vi = *reinterpret_cast<const float2*>(zi + pair * ND + lane * 2);
    const float2 vj = *reinterpret_cast<const float2*>(zj + pair * ND + lane * 2);
    float ssi = vi.x * vi.x + vi.y * vi.y;
    float ssj = vj.x * vj.x + vj.y * vj.y;
#pragma unroll
    for (int m = 1; m < 64; m <<= 1) {
        ssi += __shfl_xor(ssi, m);
        ssj += __shfl_xor(ssj, m);
    }
    float ni = fmaxf(sqrtf(ssi), 1e-12f);
    float nj = fmaxf(sqrtf(ssj), 1e-12f);
    const float ii = 1.0f / ni, ij = 1.0f / nj;
    const float uix = vi.x * ii, uiy = vi.y * ii;
    const float ujx = vj.x * ij, ujy = vj.y * ij;
    float d = uix * ujx + uiy * ujy;
#pragma unroll
    for (int m = 1; m < 64; m <<= 1) d += __shfl_xor(d, m);
    if (lane == 0) pos[pair] = d;
    // fp8 e4m3 (OCP on gfx950), pre-scaled by sqrt(C) so MFMA output = sim * C = exp2 arg
    const int pki = __builtin_amdgcn_cvt_pk_fp8_f32(uix * SQRT_C_VAL, uiy * SQRT_C_VAL, 0, false);
    const int pkj = __builtin_amdgcn_cvt_pk_fp8_f32(ujx * SQRT_C_VAL, ujy * SQRT_C_VAL, 0, false);
    reps8_u16[pair * 64 + lane] = (unsigned short)(pki & 0xFFFF);
    reps8_u16[(NB + pair) * 64 + lane] = (unsigned short)(pkj & 0xFFFF);
}

// ---------------- fused sim-GEMM (MX-fp8 K=128) + sum(exp2), upper triangle ----------------
// Exact symmetry: e_rc == e_cr bitwise (same fp8 operands, commutative products, same
// MFMA reduction tree), so each strict-upper element feeds its row sum AND col sum.
// Diagonal never computed => no sdiag correction needed.
__device__ inline void gload_lds16(const void* g, void* l) {
    __builtin_amdgcn_global_load_lds(
        (const __attribute__((address_space(1))) void*)g,
        (__attribute__((address_space(3))) void*)l, 16, 0, 0);
}

// LDS tile: 32 macro-rows x 256 B (16 slots of 16 B). Macro-row m holds cols {2m,2m+1};
// stored slot sp = s ^ ((m&3)<<1), where s = 2*chunk + (col&1). Involution => stage
// (via pre-swizzled global source, rule #21) and read use the same XOR.
__global__ __launch_bounds__(512, 4) void sim_kernel(const char* __restrict__ reps8,
                                                     float* __restrict__ ssum) {
    const int a = blockIdx.x;   // row-block (256 rows)
    const int s = blockIdx.y;   // col-strip (512 cols)
    if (2 * (s + 1) <= a) return;  // strip entirely at/below diagonal: nothing strict-upper

    __shared__ __align__(16) char lds[4][TILEB];  // 4 x 8 KiB ring
    __shared__ float cs[CPB];                     // per-block column sums (2 KiB)

    const int tid = threadIdx.x;
    const int lane = tid & 63;
    const int wid = tid >> 6;       // 0..7
    const int l15 = lane & 15;
    const int l4 = lane >> 4;
    const int rb = a * 256;           // 256 rows per block (8 waves x 32)
    const int cb = s * CPB;           // column strip
    const int qb = rb + wid * 32;     // this wave's 32 rows

    if (tid < CPB) cs[tid] = 0.f;

    // Q fragments: per lane row (qb+g*16+l15), contiguous 32 fp8 at k = 32*l4
    v8i qf[2];
#pragma unroll
    for (int g = 0; g < 2; ++g)
        qf[g] = *reinterpret_cast<const v8i*>(
            reps8 + (size_t)(qb + g * 16 + l15) * 128 + l4 * 32);
    // drain Q loads so vmcnt counts only staging loads from here on
    __builtin_amdgcn_sched_barrier(0);
    asm volatile("s_waitcnt vmcnt(0)" ::: "memory");
    __builtin_amdgcn_sched_barrier(0);

    f32x4 sacc[2];
#pragma unroll
    for (int g = 0; g < 2; ++g) sacc[g] = {0.f, 0.f, 0.f, 0.f};

    // tile-invariant per-lane staging source (1 slot of 16 B per thread)
    const int m_s = tid >> 4;                 // macro-row 0..31
    const int sp_s = tid & 15;                // stored slot
    const int s_s = sp_s ^ ((m_s & 3) << 1);  // pre-swizzle slot (involution)
    const char* srcq = reps8 + (size_t)(cb + 2 * m_s + (s_s & 1)) * 128 + (s_s >> 1) * 16;

    auto stage = [&](int t) {
        char* dst = &lds[t & 3][wid * 1024];  // wave-uniform base
        gload_lds16(srcq + (size_t)t * TILEB, dst);
    };

    // per-lane ds_read offsets (cg-invariant): macro-row m = cg*8 + h, h = l15>>1
    const int h = l15 >> 1;
    const int sloA = (4 * l4 + (l15 & 1)) ^ ((h & 3) << 1);
    const int rdlo = h * 256 + sloA * 16;         // slot sloA   (chunk 2*l4)
    const int rdhi = h * 256 + (sloA ^ 2) * 16;   // slot sloA^2 (chunk 2*l4+1)

    // prologue: 3 tiles in flight (3 loads/wave)
    stage(0);
    stage(1);
    stage(2);

#pragma unroll 1  // R18 lesson: full unroll software-pipelines all tiles -> spill
    for (int t = 0; t < NT; ++t) {
        // counted wait for tile t (per-wave own loads: 1/tile), then ONE barrier per tile
        if (t <= NT - 3) {
            asm volatile("s_waitcnt vmcnt(2)" ::: "memory");
        } else if (t == NT - 2) {
            asm volatile("s_waitcnt vmcnt(1)" ::: "memory");
        } else {
            asm volatile("s_waitcnt vmcnt(0)" ::: "memory");
        }
        __builtin_amdgcn_s_barrier();  // all waves' tile-t loads landed; compute(t-1) done
        if (t + 3 < NT) stage(t + 3);  // overwrites buf[(t-1)&3], safe after barrier

        const int tc = cb + t * CTILE;
        const bool msk = (tc <= qb + 31);  // straddle: need strict col>row masking
        const char* lbase = lds[t & 3];
        // cg order rotated per wave (wid): desyncs pipe phases AND de-contends cs atomics
#pragma unroll
        for (int cc = 0; cc < 4; ++cc) {
            const int cg = (cc + wid) & 3;
            const v4i lo = *reinterpret_cast<const v4i*>(lbase + rdlo + cg * 2048);
            const v4i hi = *reinterpret_cast<const v4i*>(lbase + rdhi + cg * 2048);
            const v8i kf = __builtin_shufflevector(lo, hi, 0, 1, 2, 3, 4, 5, 6, 7);
            const f32x4 z4 = {0.f, 0.f, 0.f, 0.f};
            f32x4 acc0 = __builtin_amdgcn_mfma_scale_f32_16x16x128_f8f6f4(
                qf[0], kf, z4, 0, 0, 0, 0x7F7F7F7F, 0, 0x7F7F7F7F);
            f32x4 acc1 = __builtin_amdgcn_mfma_scale_f32_16x16x128_f8f6f4(
                qf[1], kf, z4, 0, 0, 0, 0x7F7F7F7F, 0, 0x7F7F7F7F);
            float csum = 0.f;
            if (!msk) {
#pragma unroll
                for (int r = 0; r < 4; ++r) {
                    const float e0 = __builtin_amdgcn_exp2f(acc0[r]);
                    const float e1 = __builtin_amdgcn_exp2f(acc1[r]);
                    sacc[0][r] += e0;
                    sacc[1][r] += e1;
                    csum += e0 + e1;
                }
            } else {
                const int col_abs = tc + cg * 16 + l15;
                const int row0 = qb + l4 * 4;
#pragma unroll
                for (int r = 0; r < 4; ++r) {
                    float e0 = __builtin_amdgcn_exp2f(acc0[r]);
                    float e1 = __builtin_amdgcn_exp2f(acc1[r]);
                    e0 = (col_abs > row0 + r) ? e0 : 0.f;
                    e1 = (col_abs > row0 + 16 + r) ? e1 : 0.f;
                    sacc[0][r] += e0;
                    sacc[1][r] += e1;
                    csum += e0 + e1;
                }
            }
            // column partial sums: reduce over the 4 row-groups (l4), then LDS atomic
            csum += __shfl_xor(csum, 16);
            csum += __shfl_xor(csum, 32);
            if (lane < 16) atomicAdd(&cs[t * CTILE + cg * 16 + lane], csum);
        }
    }

    // row sums: reduce across the 16 column-lanes, then one atomic per row
#pragma unroll
    for (int g = 0; g < 2; ++g) {
#pragma unroll
        for (int r = 0; r < 4; ++r) {
#pragma unroll
            for (int m = 1; m < 16; m <<= 1) sacc[g][r] += __shfl_xor(sacc[g][r], m);
        }
    }
    if (l15 == 0) {
#pragma unroll
        for (int g = 0; g < 2; ++g)
#pragma unroll
            for (int r = 0; r < 4; ++r)
                atomicAdd(&ssum[qb + g * 16 + l4 * 4 + r], sacc[g][r]);
    }

    // column sums: one flush per block
    __syncthreads();
    if (tid < CPB) {
        const float v = cs[tid];
        if (v != 0.f) atomicAdd(&ssum[cb + tid], v);
    }
}

// ---------------- finalize: loss = mean(ln(ssum) - 2*pos) ----------------
__global__ __launch_bounds__(1024) void fin_kernel(const float* __restrict__ ssum,
                                                   const float* __restrict__ pos,
                                                   float* __restrict__ out) {
    const int tid = threadIdx.x;
    float acc = 0.f;
    for (int r = tid; r < N2; r += 1024) {
        const int p = (r < NB) ? r : r - NB;
        acc += logf(ssum[r]) - 2.0f * pos[p];
    }
#pragma unroll
    for (int m = 1; m < 64; m <<= 1) acc += __shfl_xor(acc, m);
    __shared__ float red[16];
    const int wid = tid >> 6, lane = tid & 63;
    if (lane == 0) red[wid] = acc;
    __syncthreads();
    if (wid == 0) {
        float v = (lane < 16) ? red[lane] : 0.f;
#pragma unroll
        for (int m = 1; m < 16; m <<= 1) v += __shfl_xor(v, m);
        if (lane == 0) out[0] = v / (float)N2;
    }
}

extern "C" void kernel_launch(void* const* d_in, const int* in_sizes, int n_in,
                              void* d_out, int out_size, void* d_ws, size_t ws_size,
                              hipStream_t stream) {
    const float* zi = (const float*)d_in[0];
    const float* zj = (const float*)d_in[1];
    float* out = (float*)d_out;
    char* ws = (char*)d_ws;

    char* reps8 = ws;                                      // 16384*128 = 2 MiB fp8
    float* pos = (float*)(ws + (size_t)N2 * ND);           // 8192 f32
    float* ssum = pos + NB;                                // 16384 f32

    nrm_kernel<<<NB / 4, 256, 0, stream>>>(zi, zj, (unsigned short*)reps8, pos, ssum);
    dim3 grid(N2 / 256, N2 / CPB);                         // 64 x 32; ~half exit immediately
    sim_kernel<<<grid, 512, 0, stream>>>(reps8, ssum);
    fin_kernel<<<1, 1024, 0, stream>>>(ssum, pos, out);
}

// Round 23
// 53.210 us; speedup vs baseline: 1.6082x; 1.6082x over previous
//
#include <hip/hip_runtime.h>
#include <hip/hip_bf16.h>

#define NB 8192   // B
#define ND 128    // D
#define N2 16384  // 2B

#define CPB 512               // columns per block (32-way column split)
#define CTILE 64              // columns staged per LDS tile
#define NT (CPB / CTILE)      // 8 tiles per block
#define TILEB (CTILE * 128)   // 8192 bytes per fp8 tile

typedef __attribute__((ext_vector_type(4))) float f32x4;
typedef __attribute__((ext_vector_type(4))) int v4i;
typedef __attribute__((ext_vector_type(8))) int v8i;

// sqrt((1/T) * log2(e)) with T=0.5 : sqrt(2.8853900817779268)
static constexpr float SQRT_C_VAL = 1.69864368f;

// ---------------- normalize + pos-dot + fp8 quantize + quantized self-dot ----------------
__global__ __launch_bounds__(256) void nrm_kernel(const float* __restrict__ zi,
                                                  const float* __restrict__ zj,
                                                  unsigned short* __restrict__ reps8_u16,
                                                  float* __restrict__ pos,
                                                  float* __restrict__ ssum,
                                                  float* __restrict__ sdiag,
                                                  float* __restrict__ out) {
    const int gtid = blockIdx.x * 256 + threadIdx.x;
    if (gtid < N2) ssum[gtid] = 0.f;  // replaces the hipMemsetAsync dispatch
    if (gtid == 0) out[0] = 0.f;      // fin_kernel accumulates atomically
    const int pair = gtid >> 6;
    const int lane = threadIdx.x & 63;
    const float2 vi = *reinterpret_cast<const float2*>(zi + pair * ND + lane * 2);
    const float2 vj = *reinterpret_cast<const float2*>(zj + pair * ND + lane * 2);
    float ssi = vi.x * vi.x + vi.y * vi.y;
    float ssj = vj.x * vj.x + vj.y * vj.y;
#pragma unroll
    for (int m = 1; m < 64; m <<= 1) {
        ssi += __shfl_xor(ssi, m);
        ssj += __shfl_xor(ssj, m);
    }
    float ni = fmaxf(sqrtf(ssi), 1e-12f);
    float nj = fmaxf(sqrtf(ssj), 1e-12f);
    const float ii = 1.0f / ni, ij = 1.0f / nj;
    const float uix = vi.x * ii, uiy = vi.y * ii;
    const float ujx = vj.x * ij, ujy = vj.y * ij;
    float d = uix * ujx + uiy * ujy;
#pragma unroll
    for (int m = 1; m < 64; m <<= 1) d += __shfl_xor(d, m);
    if (lane == 0) pos[pair] = d;
    // fp8 e4m3 (OCP on gfx950), pre-scaled by sqrt(C) so MFMA output = sim * C = exp2 arg
    const int pki = __builtin_amdgcn_cvt_pk_fp8_f32(uix * SQRT_C_VAL, uiy * SQRT_C_VAL, 0, false);
    const int pkj = __builtin_amdgcn_cvt_pk_fp8_f32(ujx * SQRT_C_VAL, ujy * SQRT_C_VAL, 0, false);
    reps8_u16[pair * 64 + lane] = (unsigned short)(pki & 0xFFFF);
    reps8_u16[(NB + pair) * 64 + lane] = (unsigned short)(pkj & 0xFFFF);
    // quantized self-dot (== MFMA diagonal term, exact): fin subtracts exp2(sdiag)
    const float fi0 = __builtin_amdgcn_cvt_f32_fp8(pki, 0);
    const float fi1 = __builtin_amdgcn_cvt_f32_fp8(pki, 1);
    const float fj0 = __builtin_amdgcn_cvt_f32_fp8(pkj, 0);
    const float fj1 = __builtin_amdgcn_cvt_f32_fp8(pkj, 1);
    float sqi = fi0 * fi0 + fi1 * fi1;
    float sqj = fj0 * fj0 + fj1 * fj1;
#pragma unroll
    for (int m = 1; m < 64; m <<= 1) {
        sqi += __shfl_xor(sqi, m);
        sqj += __shfl_xor(sqj, m);
    }
    if (lane == 0) {
        sdiag[pair] = sqi;
        sdiag[NB + pair] = sqj;
    }
}

// ---------------- fused sim-GEMM (MX-fp8 K=128) + sum(exp2), phase-desynced waves ----------------
__device__ inline void gload_lds16(const void* g, void* l) {
    __builtin_amdgcn_global_load_lds(
        (const __attribute__((address_space(1))) void*)g,
        (__attribute__((address_space(3))) void*)l, 16, 0, 0);
}

// LDS tile: 32 macro-rows x 256 B (16 slots of 16 B). Macro-row m holds cols {2m,2m+1};
// stored slot sp = s ^ ((m&3)<<1), where s = 2*chunk + (col&1). Involution => stage
// (via pre-swizzled global source, rule #21) and read use the same XOR.
__global__ __launch_bounds__(512, 4) void sim_kernel(const char* __restrict__ reps8,
                                                     float* __restrict__ ssum) {
    __shared__ __align__(16) char lds[4][TILEB];  // 4 x 8 KiB ring
    const int tid = threadIdx.x;
    const int lane = tid & 63;
    const int wid = tid >> 6;       // 0..7
    const int l15 = lane & 15;
    const int l4 = lane >> 4;
    const int rb = blockIdx.x * 256;  // 256 rows per block (8 waves x 32)
    const int cb = blockIdx.y * CPB;  // column split
    const int qb = rb + wid * 32;     // this wave's 32 rows

    // Q fragments: per lane row (qb+g*16+l15), contiguous 32 fp8 at k = 32*l4
    v8i qf[2];
#pragma unroll
    for (int g = 0; g < 2; ++g)
        qf[g] = *reinterpret_cast<const v8i*>(
            reps8 + (size_t)(qb + g * 16 + l15) * 128 + l4 * 32);
    // drain Q loads so vmcnt counts only staging loads from here on
    __builtin_amdgcn_sched_barrier(0);
    asm volatile("s_waitcnt vmcnt(0)" ::: "memory");
    __builtin_amdgcn_sched_barrier(0);

    f32x4 sacc[2];
#pragma unroll
    for (int g = 0; g < 2; ++g) sacc[g] = {0.f, 0.f, 0.f, 0.f};

    // tile-invariant per-lane staging source (1 slot of 16 B per thread)
    const int m_s = tid >> 4;                 // macro-row 0..31
    const int sp_s = tid & 15;                // stored slot
    const int s_s = sp_s ^ ((m_s & 3) << 1);  // pre-swizzle slot (involution)
    const char* srcq = reps8 + (size_t)(cb + 2 * m_s + (s_s & 1)) * 128 + (s_s >> 1) * 16;

    auto stage = [&](int t) {
        char* dst = &lds[t & 3][wid * 1024];  // wave-uniform base
        gload_lds16(srcq + (size_t)t * TILEB, dst);
    };

    // per-lane ds_read offsets (cg-invariant): macro-row m = cg*8 + h, h = l15>>1
    const int h = l15 >> 1;
    const int sloA = (4 * l4 + (l15 & 1)) ^ ((h & 3) << 1);
    const int rdlo = h * 256 + sloA * 16;         // slot sloA   (chunk 2*l4)
    const int rdhi = h * 256 + (sloA ^ 2) * 16;   // slot sloA^2 (chunk 2*l4+1)

    // prologue: 3 tiles in flight (3 loads/wave)
    stage(0);
    stage(1);
    stage(2);

#pragma unroll 1  // R18 lesson: full unroll software-pipelines all tiles -> spill
    for (int t = 0; t < NT; ++t) {
        // counted wait for tile t (per-wave own loads: 1/tile), then ONE barrier per tile
        if (t <= NT - 3) {
            asm volatile("s_waitcnt vmcnt(2)" ::: "memory");
        } else if (t == NT - 2) {
            asm volatile("s_waitcnt vmcnt(1)" ::: "memory");
        } else {
            asm volatile("s_waitcnt vmcnt(0)" ::: "memory");
        }
        __builtin_amdgcn_s_barrier();  // all waves' tile-t loads landed; compute(t-1) done
        if (t + 3 < NT) stage(t + 3);  // overwrites buf[(t-1)&3], safe after barrier

        const char* lbase = lds[t & 3];
        // uniform compute; cg order rotated per wave (wid) to desync pipe phases
#pragma unroll
        for (int cc = 0; cc < 4; ++cc) {
            const int cg = (cc + wid) & 3;
            const v4i lo = *reinterpret_cast<const v4i*>(lbase + rdlo + cg * 2048);
            const v4i hi = *reinterpret_cast<const v4i*>(lbase + rdhi + cg * 2048);
            const v8i kf = __builtin_shufflevector(lo, hi, 0, 1, 2, 3, 4, 5, 6, 7);
            const f32x4 z4 = {0.f, 0.f, 0.f, 0.f};
            __builtin_amdgcn_s_setprio(1);
            f32x4 acc0 = __builtin_amdgcn_mfma_scale_f32_16x16x128_f8f6f4(
                qf[0], kf, z4, 0, 0, 0, 0x7F7F7F7F, 0, 0x7F7F7F7F);
            f32x4 acc1 = __builtin_amdgcn_mfma_scale_f32_16x16x128_f8f6f4(
                qf[1], kf, z4, 0, 0, 0, 0x7F7F7F7F, 0, 0x7F7F7F7F);
            __builtin_amdgcn_s_setprio(0);
            f32x4 e0, e1;
#pragma unroll
            for (int r = 0; r < 4; ++r) {
                e0[r] = __builtin_amdgcn_exp2f(acc0[r]);
                e1[r] = __builtin_amdgcn_exp2f(acc1[r]);
            }
            sacc[0] += e0;  // vector adds -> v_pk_add_f32 (half the add issue)
            sacc[1] += e1;
        }
    }

    // reduce across the 16 column-lanes, then one atomic per row
#pragma unroll
    for (int g = 0; g < 2; ++g) {
#pragma unroll
        for (int r = 0; r < 4; ++r) {
#pragma unroll
            for (int m = 1; m < 16; m <<= 1) sacc[g][r] += __shfl_xor(sacc[g][r], m);
        }
    }
    if (l15 == 0) {
#pragma unroll
        for (int g = 0; g < 2; ++g)
#pragma unroll
            for (int r = 0; r < 4; ++r)
                atomicAdd(&ssum[qb + g * 16 + l4 * 4 + r], sacc[g][r]);
    }
}

// ---------------- finalize: loss = mean(ln(ssum - exp2(sdiag)) - 2*pos), distributed ----------------
__global__ __launch_bounds__(1024) void fin_kernel(const float* __restrict__ ssum,
                                                   const float* __restrict__ pos,
                                                   const float* __restrict__ sdiag,
                                                   float* __restrict__ out) {
    const int tid = threadIdx.x;
    const int r0 = blockIdx.x * (N2 / 16);  // 16 blocks x 1024 rows
    float acc = 0.f;
    for (int i = tid; i < N2 / 16; i += 1024) {
        const int r = r0 + i;
        const int p = (r < NB) ? r : r - NB;
        acc += logf(ssum[r] - exp2f(sdiag[r])) - 2.0f * pos[p];
    }
#pragma unroll
    for (int m = 1; m < 64; m <<= 1) acc += __shfl_xor(acc, m);
    __shared__ float red[16];
    const int wid = tid >> 6, lane = tid & 63;
    if (lane == 0) red[wid] = acc;
    __syncthreads();
    if (wid == 0) {
        float v = (lane < 16) ? red[lane] : 0.f;
#pragma unroll
        for (int m = 1; m < 16; m <<= 1) v += __shfl_xor(v, m);
        if (lane == 0) atomicAdd(out, v / (float)N2);
    }
}

extern "C" void kernel_launch(void* const* d_in, const int* in_sizes, int n_in,
                              void* d_out, int out_size, void* d_ws, size_t ws_size,
                              hipStream_t stream) {
    const float* zi = (const float*)d_in[0];
    const float* zj = (const float*)d_in[1];
    float* out = (float*)d_out;
    char* ws = (char*)d_ws;

    char* reps8 = ws;                                      // 16384*128 = 2 MiB fp8
    float* pos = (float*)(ws + (size_t)N2 * ND);           // 8192 f32
    float* ssum = pos + NB;                                // 16384 f32
    float* sdiag = ssum + N2;                              // 16384 f32

    nrm_kernel<<<NB / 4, 256, 0, stream>>>(zi, zj, (unsigned short*)reps8, pos, ssum, sdiag, out);
    dim3 grid(N2 / 256, N2 / CPB);
    sim_kernel<<<grid, 512, 0, stream>>>(reps8, ssum);
    fin_kernel<<<16, 1024, 0, stream>>>(ssum, pos, sdiag, out);
}